// Round 6
// baseline (115.034 us; speedup 1.0000x reference)
//
#include <hip/hip_runtime.h>
#include <hip/hip_bf16.h>
#include <stdint.h>
#include <string.h>

typedef unsigned short u16;
typedef __attribute__((ext_vector_type(4))) float f32x4;
typedef __attribute__((ext_vector_type(8))) short s16x8;
typedef __attribute__((ext_vector_type(4))) short s16x4;

#define DEVFN __device__ __forceinline__

// B=2, T=2048, C=1024, N=16, D=64, M=B*T=4096
DEVFN u16 f2bf(float f){
    union { float f; uint32_t u; } x; x.f = f;
    uint32_t u = x.u;
    return (u16)((u + 0x7fffu + ((u >> 16) & 1u)) >> 16);   // RNE
}
DEVFN u16 f2bf_h(float f){
    __hip_bfloat16 h = __float2bfloat16(f);
    u16 r; memcpy(&r, &h, 2); return r;
}
DEVFN float bf2f(u16 v){
    union { uint32_t u; float f; } x; x.u = (uint32_t)v << 16; return x.f;
}

DEVFN void gl_lds16(const void* g, void* l){
    __builtin_amdgcn_global_load_lds((const __attribute__((address_space(1))) void*)g,
                                     (__attribute__((address_space(3))) void*)l, 16, 0, 0);
}

// chunk-cumulative offset for qt>=4 (128-row q-tiles, chunks of 8 kv-tiles)
DEVFN int cumch(int qt){
    int b = qt >> 2;                          // 1,2,3
    int start = (b == 1) ? 0 : (b == 2) ? 8 : 20;
    return start + (qt - b * 4) * (b + 1);
}

// softmax scale folded into Q at QKV-GEMM epilogue
#define SOFTMAX_SC 0.18033688011112042f   // log2(e)/sqrt(64)

// ---------------- convert x (fp32 -> bf16) ----------------
__global__ void k_cvt_x(const float* __restrict__ x, u16* __restrict__ xb){
    int i = (blockIdx.x * 256 + threadIdx.x) * 8;
    f32x4 a = *(const f32x4*)(x + i);
    f32x4 b = *(const f32x4*)(x + i + 4);
    s16x8 o;
    o[0]=f2bf(a[0]); o[1]=f2bf(a[1]); o[2]=f2bf(a[2]); o[3]=f2bf(a[3]);
    o[4]=f2bf(b[0]); o[5]=f2bf(b[1]); o[6]=f2bf(b[2]); o[7]=f2bf(b[3]);
    *(s16x8*)(xb + i) = o;
}

// ---------------- transpose+convert weights: Wt[n][k] = W[k][n] ----------------
__global__ void k_cvt_wt(const float* __restrict__ w0, const float* __restrict__ w1,
                         const float* __restrict__ w2, const float* __restrict__ w3,
                         u16* __restrict__ oqkv, u16* __restrict__ op){
    int z = blockIdx.z;
    const float* w = z==0 ? w0 : z==1 ? w1 : z==2 ? w2 : w3;
    u16* o = (z==3) ? op : (oqkv + (size_t)z * 1024 * 1024);
    __shared__ __align__(16) float t[64][65];
    int tid = threadIdx.x;
    int n0 = blockIdx.x * 64, k0 = blockIdx.y * 64;
    for (int rr = 0; rr < 4; rr++){
        int r = rr * 16 + (tid >> 4);
        int c = (tid & 15) * 4;
        f32x4 v = *(const f32x4*)(w + (size_t)(k0 + r) * 1024 + n0 + c);
        t[r][c] = v[0]; t[r][c+1] = v[1]; t[r][c+2] = v[2]; t[r][c+3] = v[3];
    }
    __syncthreads();
    int n = tid >> 2, kc = (tid & 3) * 16;
    s16x8 a, b;
    #pragma unroll
    for (int j = 0; j < 8; j++) a[j] = f2bf(t[kc + j][n]);
    #pragma unroll
    for (int j = 0; j < 8; j++) b[j] = f2bf(t[kc + 8 + j][n]);
    u16* dst = o + (size_t)(n0 + n) * 1024 + k0 + kc;
    *(s16x8*)dst = a;
    *(s16x8*)(dst + 8) = b;
}

// ---------------- QKV GEMM: [4096,1024] x Wt[3072,1024]^T ----------------
__global__ __launch_bounds__(256, 3) void k_gemm_qkv(
    const u16* __restrict__ A, const u16* __restrict__ Bt,
    const float* __restrict__ bq, const float* __restrict__ bk, const float* __restrict__ bv,
    u16* __restrict__ Qb, u16* __restrict__ Kb, u16* __restrict__ Vt)
{
    __shared__ __align__(16) union { u16 st[2][128 * 64]; float epi[2][64 * 68]; } sm;
    const int tid = threadIdx.x, w = tid >> 6, lane = tid & 63;
    const int id = (int)blockIdx.x;
    const int p = id >> 3;
    const int m0 = ((id & 7) * 4 + (p & 3)) * 128;
    const int n0 = (p >> 2) * 128;
    const int wr = w >> 1, wc = w & 1;
    const int l15 = lane & 15, g = lane >> 4, r8 = lane >> 3, ch = lane & 7;

    f32x4 acc[4][4];
    #pragma unroll
    for (int i = 0; i < 4; i++)
        #pragma unroll
        for (int j = 0; j < 4; j++) acc[i][j] = (f32x4){0.f, 0.f, 0.f, 0.f};

    for (int kt = 0; kt < 16; ++kt){
        #pragma unroll
        for (int c = 0; c < 4; c++){
            int row = w * 32 + c * 8 + r8;
            int sw = ch ^ (row & 7);
            gl_lds16(A  + (size_t)(m0 + row) * 1024 + kt * 64 + sw * 8, &sm.st[0][(w * 32 + c * 8) * 64]);
            gl_lds16(Bt + (size_t)(n0 + row) * 1024 + kt * 64 + sw * 8, &sm.st[1][(w * 32 + c * 8) * 64]);
        }
        __syncthreads();
        const u16* sa = sm.st[0];
        const u16* sb = sm.st[1];
        #pragma unroll
        for (int kk = 0; kk < 2; kk++){
            s16x8 af[4], bf[4];
            #pragma unroll
            for (int i = 0; i < 4; i++){
                int row = wr * 64 + i * 16 + l15;
                int cidx = (kk * 4 + g) ^ (row & 7);
                af[i] = *(const s16x8*)&sa[row * 64 + cidx * 8];
            }
            #pragma unroll
            for (int j = 0; j < 4; j++){
                int row = wc * 64 + j * 16 + l15;
                int cidx = (kk * 4 + g) ^ (row & 7);
                bf[j] = *(const s16x8*)&sb[row * 64 + cidx * 8];
            }
            #pragma unroll
            for (int i = 0; i < 4; i++)
                #pragma unroll
                for (int j = 0; j < 4; j++)
                    acc[i][j] = __builtin_amdgcn_mfma_f32_16x16x32_bf16(af[i], bf[j], acc[i][j], 0, 0, 0);
        }
        __syncthreads();
    }

    const int which = n0 >> 10;           // 0=Q,1=K,2=V
    const int c0 = (n0 & 1023) + wc * 64; // col within C
    const float* bias = which == 0 ? bq : which == 1 ? bk : bv;

    if (which == 2){
        #pragma unroll
        for (int j = 0; j < 4; j++){
            int cg = c0 + j * 16 + l15;
            float bb = bias[cg];
            int h = cg >> 6, d = cg & 63;
            #pragma unroll
            for (int i = 0; i < 4; i++){
                int mg = m0 + wr * 64 + i * 16 + g * 4;
                int bI = mg >> 11, tt0 = mg & 2047;
                s16x4 pk;
                #pragma unroll
                for (int r = 0; r < 4; r++) pk[r] = f2bf(acc[i][j][r] + bb);
                *(s16x4*)(Vt + ((size_t)(bI * 16 + h) * 64 + d) * 2048 + tt0) = pk;
            }
        }
    } else {
        u16* Ob = which == 0 ? Qb : Kb;
        const float scl = (which == 0) ? SOFTMAX_SC : 1.0f;   // fold softmax scale into Q
        float* ep = sm.epi[w & 1];
        float bb[4];
        #pragma unroll
        for (int j = 0; j < 4; j++) bb[j] = bias[c0 + j * 16 + l15];
        #pragma unroll
        for (int half = 0; half < 2; half++){
            __syncthreads();
            if ((w >> 1) == half){
                #pragma unroll
                for (int i = 0; i < 4; i++)
                    #pragma unroll
                    for (int j = 0; j < 4; j++)
                        #pragma unroll
                        for (int r = 0; r < 4; r++)
                            ep[(i * 16 + g * 4 + r) * 68 + j * 16 + l15] = (acc[i][j][r] + bb[j]) * scl;
                #pragma unroll
                for (int rr = 0; rr < 8; rr++){
                    int rowl = rr * 8 + r8;
                    const float* src = &ep[rowl * 68 + ch * 8];
                    f32x4 v0 = *(const f32x4*)src;
                    f32x4 v1 = *(const f32x4*)(src + 4);
                    s16x8 o;
                    o[0]=f2bf(v0[0]); o[1]=f2bf(v0[1]); o[2]=f2bf(v0[2]); o[3]=f2bf(v0[3]);
                    o[4]=f2bf(v1[0]); o[5]=f2bf(v1[1]); o[6]=f2bf(v1[2]); o[7]=f2bf(v1[3]);
                    *(s16x8*)(Ob + (size_t)(m0 + wr * 64 + rowl) * 1024 + c0 + ch * 8) = o;
                }
            }
        }
    }
}

// ---------------- causal flash attention: QBLK=128 (4 waves x 32 q-rows) ----------------
// Per tile each wave reads K/V frags ONCE and runs 2 Q fragments against them.
// Split-K: chunks of 8 kv-tiles; 40 units/head, big-first within per-XCD stripes.
__global__ __launch_bounds__(256, 3) void k_attn(
    const u16* __restrict__ Qb, const u16* __restrict__ Kb,
    const u16* __restrict__ Vt, u16* __restrict__ Ob,
    u16* __restrict__ Part, float* __restrict__ Ml)
{
    __shared__ __align__(16) u16 sK[2][64 * 64];
    __shared__ __align__(16) u16 sV[2][64 * 64];
    __shared__ __align__(16) u16 sP[4][32 * 64];
    const int tid = threadIdx.x, w = tid >> 6, lane = tid & 63;
    const int l15 = lane & 15, g = lane >> 4, r8 = lane >> 3, ch8 = lane & 7;

    // per-XCD stripe of 160 units (4 heads x 40), big units first
    const int phys = (int)blockIdx.x;
    const int stripe = phys & 7;
    const int idx = phys >> 3;           // 0..159
    const int hl = idx & 3;
    const int u = 39 - (idx >> 2);       // 39..0, big first
    const int bh = stripe * 4 + hl;

    int band, base;
    if (u < 4)       { band = 0; base = 0;  }
    else if (u < 12) { band = 1; base = 4;  }
    else if (u < 24) { band = 2; base = 12; }
    else             { band = 3; base = 24; }
    const int off = u - base;
    const int qt = band * 4 + off / (band + 1);
    const int ck = off - (off / (band + 1)) * (band + 1);

    const int bb = bh >> 4, h = bh & 15;
    const int qt0 = qt * 128;
    const int ntk = 2 * qt + 2;
    const int t0 = ck * 8, te = min(t0 + 8, ntk);

    // Q fragments: qf[qh][kk], 32 q-rows per wave
    const size_t qbase = (size_t)(bb * 2048 + qt0 + w * 32 + l15) * 1024 + h * 64;
    s16x8 qf00 = *(const s16x8*)(Qb + qbase + g * 8);
    s16x8 qf01 = *(const s16x8*)(Qb + qbase + 32 + g * 8);
    s16x8 qf10 = *(const s16x8*)(Qb + qbase + 16 * 1024 + g * 8);
    s16x8 qf11 = *(const s16x8*)(Qb + qbase + 16 * 1024 + 32 + g * 8);

    auto stage = [&](int it, int bsel){
        int kv0 = it * 64;
        #pragma unroll
        for (int c = 0; c < 2; c++){
            int row = w * 16 + c * 8 + r8;
            int sw = ch8 ^ (row & 7);
            gl_lds16(Kb + (size_t)(bb * 2048 + kv0 + row) * 1024 + h * 64 + sw * 8, &sK[bsel][(w * 16 + c * 8) * 64]);
            gl_lds16(Vt + ((size_t)bh * 64 + row) * 2048 + kv0 + sw * 8,            &sV[bsel][(w * 16 + c * 8) * 64]);
        }
    };

    f32x4 o[4][2];
    #pragma unroll
    for (int f = 0; f < 4; f++){ o[f][0] = (f32x4){0.f,0.f,0.f,0.f}; o[f][1] = (f32x4){0.f,0.f,0.f,0.f}; }
    f32x4 l40 = (f32x4){0.f,0.f,0.f,0.f}, l41 = (f32x4){0.f,0.f,0.f,0.f};

    stage(t0, 0);
    __syncthreads();
    for (int it = t0; it < te; ++it){
        const int il = it - t0;
        if (it + 1 < te) stage(it + 1, (il + 1) & 1);
        const u16* kb = sK[il & 1];
        const u16* vb = sV[il & 1];
        const int kv0 = it * 64;

        // S^T = K @ Q^T: st[f][qh], lane holds col t=qh*16+l15(+w*32), rows s=f*16+4g+r
        f32x4 st[4][2];
        #pragma unroll
        for (int f = 0; f < 4; f++){ st[f][0] = (f32x4){0.f,0.f,0.f,0.f}; st[f][1] = (f32x4){0.f,0.f,0.f,0.f}; }
        __builtin_amdgcn_s_setprio(1);
        #pragma unroll
        for (int kk = 0; kk < 2; kk++){
            s16x8 q0 = kk ? qf01 : qf00;
            s16x8 q1 = kk ? qf11 : qf10;
            #pragma unroll
            for (int f = 0; f < 4; f++){
                int row = f * 16 + l15;
                int cidx = (kk * 4 + g) ^ (row & 7);
                s16x8 kf = *(const s16x8*)&kb[row * 64 + cidx * 8];
                st[f][0] = __builtin_amdgcn_mfma_f32_16x16x32_bf16(kf, q0, st[f][0], 0, 0, 0);
                st[f][1] = __builtin_amdgcn_mfma_f32_16x16x32_bf16(kf, q1, st[f][1], 0, 0, 0);
            }
        }
        __builtin_amdgcn_s_setprio(0);
        if (it >= 2 * qt){   // tiles overlapping/beyond the diagonal: causal mask
            #pragma unroll
            for (int qh = 0; qh < 2; qh++){
                int t_my = qt0 + w * 32 + qh * 16 + l15;
                #pragma unroll
                for (int f = 0; f < 4; f++)
                    #pragma unroll
                    for (int r = 0; r < 4; r++){
                        int s_idx = kv0 + f * 16 + g * 4 + r;
                        if (s_idx > t_my) st[f][qh][r] = -1e30f;
                    }
            }
        }
        // fixed-max softmax: p = exp2(st) (Q pre-scaled), per-lane partial l
        #pragma unroll
        for (int f = 0; f < 4; f++)
            #pragma unroll
            for (int qh = 0; qh < 2; qh++)
                #pragma unroll
                for (int r = 0; r < 4; r++) st[f][qh][r] = exp2f(st[f][qh][r]);
        l40 += (st[0][0] + st[1][0]) + (st[2][0] + st[3][0]);
        l41 += (st[0][1] + st[1][1]) + (st[2][1] + st[3][1]);
        // P^T -> LDS (per-wave 4KB buffer, XOR-swizzled rows)
        #pragma unroll
        for (int qh = 0; qh < 2; qh++){
            char* pbase = (char*)&sP[w][0] + (qh * 16 + l15) * 128;
            #pragma unroll
            for (int f = 0; f < 4; f++){
                s16x4 pk;
                #pragma unroll
                for (int r = 0; r < 4; r++) pk[r] = (short)f2bf_h(st[f][qh][r]);
                *(s16x4*)(pbase + ((f * 32 + g * 8) ^ ((l15 & 7) << 4))) = pk;
            }
        }
        // O^T += V^T @ P^T (shared V frags, 2 P fragments)
        __builtin_amdgcn_s_setprio(1);
        #pragma unroll
        for (int kk = 0; kk < 2; kk++){
            s16x8 pf0 = *(const s16x8*)((char*)&sP[w][0] + (l15) * 128      + ((kk * 64 + g * 16) ^ ((l15 & 7) << 4)));
            s16x8 pf1 = *(const s16x8*)((char*)&sP[w][0] + (16 + l15) * 128 + ((kk * 64 + g * 16) ^ ((l15 & 7) << 4)));
            #pragma unroll
            for (int f = 0; f < 4; f++){
                int row = f * 16 + l15;
                int cidx = (kk * 4 + g) ^ (row & 7);
                s16x8 vf = *(const s16x8*)&vb[row * 64 + cidx * 8];
                o[f][0] = __builtin_amdgcn_mfma_f32_16x16x32_bf16(vf, pf0, o[f][0], 0, 0, 0);
                o[f][1] = __builtin_amdgcn_mfma_f32_16x16x32_bf16(vf, pf1, o[f][1], 0, 0, 0);
            }
        }
        __builtin_amdgcn_s_setprio(0);
        __syncthreads();
    }

    // cross-lane l combine (once)
    float lr0 = (l40[0] + l40[1]) + (l40[2] + l40[3]);
    float lr1 = (l41[0] + l41[1]) + (l41[2] + l41[3]);
    lr0 += __shfl_xor(lr0, 16, 64); lr0 += __shfl_xor(lr0, 32, 64);
    lr1 += __shfl_xor(lr1, 16, 64); lr1 += __shfl_xor(lr1, 32, 64);

    if (qt < 4){   // single chunk: final output
        #pragma unroll
        for (int qh = 0; qh < 2; qh++){
            float inv = 1.0f / (qh ? lr1 : lr0);
            const size_t orow = (size_t)(bb * 2048 + qt0 + w * 32 + qh * 16 + l15) * 1024 + h * 64;
            #pragma unroll
            for (int f = 0; f < 4; f++){
                s16x4 pk;
                #pragma unroll
                for (int r = 0; r < 4; r++) pk[r] = (short)f2bf_h(o[f][qh][r] * inv);
                *(s16x4*)(Ob + orow + f * 16 + g * 4) = pk;
            }
        }
    } else {
        const int slot = bh * 36 + cumch(qt) + ck;
        u16* Op = Part + (size_t)slot * 8192;
        #pragma unroll
        for (int qh = 0; qh < 2; qh++){
            const int tl = w * 32 + qh * 16 + l15;
            #pragma unroll
            for (int f = 0; f < 4; f++){
                s16x4 pk;
                #pragma unroll
                for (int r = 0; r < 4; r++) pk[r] = (short)f2bf_h(o[f][qh][r]);
                *(s16x4*)(Op + tl * 64 + f * 16 + g * 4) = pk;
            }
            if (g == 0) Ml[slot * 128 + tl] = qh ? lr1 : lr0;
        }
    }
}

// ---------------- split-K reduce: unit-weight combine of up to 4 partials ----------------
__global__ __launch_bounds__(256) void k_reduce(
    const u16* __restrict__ Part, const float* __restrict__ Ml, u16* __restrict__ Ob)
{
    const int qt = 4 + (int)blockIdx.x;     // 4..15
    const int bh = blockIdx.y, bb = bh >> 4, h = bh & 15;
    const int nch = (qt >> 2) + 1;
    const int tid = threadIdx.x;
    const int row = tid >> 1, ds = (tid & 1) * 32;
    const int slot0 = bh * 36 + cumch(qt);

    float L = 0.f;
    #pragma unroll
    for (int c = 0; c < 4; c++)
        if (c < nch) L += Ml[(slot0 + c) * 128 + row];

    float acc[32];
    #pragma unroll
    for (int i = 0; i < 32; i++) acc[i] = 0.f;
    #pragma unroll
    for (int c = 0; c < 4; c++)
        if (c < nch){
            const u16* p = Part + (size_t)(slot0 + c) * 8192 + row * 64 + ds;
            #pragma unroll
            for (int v = 0; v < 4; v++){
                s16x8 a = *(const s16x8*)(p + v * 8);
                #pragma unroll
                for (int i = 0; i < 8; i++) acc[v * 8 + i] += bf2f((u16)a[i]);
            }
        }
    float inv = 1.0f / L;
    u16* dst = Ob + (size_t)(bb * 2048 + qt * 128 + row) * 1024 + h * 64 + ds;
    #pragma unroll
    for (int v = 0; v < 4; v++){
        s16x8 oa;
        #pragma unroll
        for (int i = 0; i < 8; i++) oa[i] = (short)f2bf_h(acc[v * 8 + i] * inv);
        *(s16x8*)(dst + v * 8) = oa;
    }
}

// ---------------- output projection -> fp32 d_out ----------------
__global__ __launch_bounds__(256, 4) void k_gemm_proj(
    const u16* __restrict__ A, const u16* __restrict__ Bt,
    const float* __restrict__ bp, float* __restrict__ Out)
{
    __shared__ __align__(16) union {
        struct { u16 a[64 * 64]; u16 b[128 * 64]; } st;
        float epi[2][32 * 68];
    } sm;
    const int tid = threadIdx.x, w = tid >> 6, lane = tid & 63;
    const int id = (int)blockIdx.x;
    const int p = id >> 3;
    const int m0 = ((id & 7) * 8 + (p & 7)) * 64;   // XCD m-slab: 8 tiles = 512 rows
    const int n0 = (p >> 3) * 128;
    const int wr = w >> 1, wc = w & 1;
    const int l15 = lane & 15, g = lane >> 4, r8 = lane >> 3, ch = lane & 7;

    f32x4 acc[2][4];
    #pragma unroll
    for (int i = 0; i < 2; i++)
        #pragma unroll
        for (int j = 0; j < 4; j++) acc[i][j] = (f32x4){0.f, 0.f, 0.f, 0.f};

    for (int kt = 0; kt < 16; ++kt){
        #pragma unroll
        for (int c = 0; c < 2; c++){
            int row = w * 16 + c * 8 + r8;
            int sw = ch ^ (row & 7);
            gl_lds16(A + (size_t)(m0 + row) * 1024 + kt * 64 + sw * 8, &sm.st.a[(w * 16 + c * 8) * 64]);
        }
        #pragma unroll
        for (int c = 0; c < 4; c++){
            int row = w * 32 + c * 8 + r8;
            int sw = ch ^ (row & 7);
            gl_lds16(Bt + (size_t)(n0 + row) * 1024 + kt * 64 + sw * 8, &sm.st.b[(w * 32 + c * 8) * 64]);
        }
        __syncthreads();
        #pragma unroll
        for (int kk = 0; kk < 2; kk++){
            s16x8 af[2], bf[4];
            #pragma unroll
            for (int i = 0; i < 2; i++){
                int row = wr * 32 + i * 16 + l15;
                int cidx = (kk * 4 + g) ^ (row & 7);
                af[i] = *(const s16x8*)&sm.st.a[row * 64 + cidx * 8];
            }
            #pragma unroll
            for (int j = 0; j < 4; j++){
                int row = wc * 64 + j * 16 + l15;
                int cidx = (kk * 4 + g) ^ (row & 7);
                bf[j] = *(const s16x8*)&sm.st.b[row * 64 + cidx * 8];
            }
            #pragma unroll
            for (int i = 0; i < 2; i++)
                #pragma unroll
                for (int j = 0; j < 4; j++)
                    acc[i][j] = __builtin_amdgcn_mfma_f32_16x16x32_bf16(af[i], bf[j], acc[i][j], 0, 0, 0);
        }
        __syncthreads();
    }

    const int c0 = n0 + wc * 64;
    float* ep = sm.epi[w & 1];
    float bb[4];
    #pragma unroll
    for (int j = 0; j < 4; j++) bb[j] = bp[c0 + j * 16 + l15];
    #pragma unroll
    for (int half = 0; half < 2; half++){
        __syncthreads();
        if ((w >> 1) == half){
            #pragma unroll
            for (int i = 0; i < 2; i++)
                #pragma unroll
                for (int j = 0; j < 4; j++)
                    #pragma unroll
                    for (int r = 0; r < 4; r++)
                        ep[(i * 16 + g * 4 + r) * 68 + j * 16 + l15] = acc[i][j][r] + bb[j];
            #pragma unroll
            for (int rr = 0; rr < 8; rr++){
                int rowl = rr * 4 + g;
                f32x4 v = *(const f32x4*)&ep[rowl * 68 + l15 * 4];
                *(f32x4*)(Out + (size_t)(m0 + wr * 32 + rowl) * 1024 + c0 + l15 * 4) = v;
            }
        }
    }
}

extern "C" void kernel_launch(void* const* d_in, const int* in_sizes, int n_in,
                              void* d_out, int out_size, void* d_ws, size_t ws_size,
                              hipStream_t stream)
{
    const float* x  = (const float*)d_in[0];
    const float* Wq = (const float*)d_in[1];
    const float* bq = (const float*)d_in[2];
    const float* Wk = (const float*)d_in[3];
    const float* bk = (const float*)d_in[4];
    const float* Wv = (const float*)d_in[5];
    const float* bv = (const float*)d_in[6];
    const float* Wp = (const float*)d_in[7];
    const float* bp = (const float*)d_in[8];
    float* out = (float*)d_out;

    char* ws = (char*)d_ws;
    u16*   xb   = (u16*)(ws);                 // 8MB  [0,8)
    u16*   Wtq  = (u16*)(ws + (8u  << 20));   // 6MB  [8,14)
    u16*   Wpt  = (u16*)(ws + (14u << 20));   // 2MB  [14,16)
    u16*   Qb   = (u16*)(ws + (16u << 20));   // 8MB  [16,24)
    u16*   Kb   = (u16*)(ws + (24u << 20));   // 8MB  [24,32)
    u16*   Vt   = (u16*)(ws + (32u << 20));   // 8MB  [32,40)
    u16*   Part = (u16*)(ws + (40u << 20));   // 1152 slots * 16KB = 18MB [40,58)
    float* Ml   = (float*)(ws + (59u << 20)); // 1152 * 128 * 4B = 0.6MB [59,59.6)
    u16*   Ob   = xb;                         // reuse x_bf16 region (dead after QKV GEMM)

    k_cvt_x   <<<dim3(2048),      dim3(256), 0, stream>>>(x, xb);
    k_cvt_wt  <<<dim3(16, 16, 4), dim3(256), 0, stream>>>(Wq, Wk, Wv, Wp, Wtq, Wpt);
    k_gemm_qkv<<<dim3(768),       dim3(256), 0, stream>>>(xb, Wtq, bq, bk, bv, Qb, Kb, Vt);
    k_attn    <<<dim3(1280),      dim3(256), 0, stream>>>(Qb, Kb, Vt, Ob, Part, Ml);
    k_reduce  <<<dim3(12, 32),    dim3(256), 0, stream>>>(Part, Ml, Ob);
    k_gemm_proj<<<dim3(512),      dim3(256), 0, stream>>>(Ob, Wpt, bp, out);
}